// Round 3
// baseline (929.449 us; speedup 1.0000x reference)
//
#include <hip/hip_runtime.h>
#include <hip/hip_bf16.h>

typedef short s16x8 __attribute__((ext_vector_type(8)));
typedef float f32x4 __attribute__((ext_vector_type(4)));

#define NTOK 16384           // H*W per batch
#define MROWS 65536          // b * NTOK

__device__ __forceinline__ float bf2f(unsigned short u) {
  union { unsigned int i; float f; } v; v.i = ((unsigned int)u) << 16; return v.f;
}
__device__ __forceinline__ unsigned short f2bf(float f) {
  union { float f; unsigned int i; } v; v.f = f;
  unsigned int x = v.i;
  return (unsigned short)((x + 0x7fffu + ((x >> 16) & 1u)) >> 16);
}

// ---------------------------------------------------------------------------
// Transpose+convert a 512x512 fp32 weight to bf16: Wt[n][k] = W[k][n]
__global__ void transpose512(const float* __restrict__ W,
                             unsigned short* __restrict__ Wt) {
  int idx = blockIdx.x * 256 + threadIdx.x;   // = n*512 + k
  int n = idx >> 9, k = idx & 511;
  Wt[idx] = f2bf(W[k * 512 + n]);
}

// fp32 -> bf16 bulk convert (4 elems/thread)
__global__ void convert_bf16(const float* __restrict__ in,
                             unsigned short* __restrict__ out) {
  size_t i = ((size_t)blockIdx.x * 256 + threadIdx.x) * 4;
  float4 f = *(const float4*)&in[i];
  unsigned short u[4] = {f2bf(f.x), f2bf(f.y), f2bf(f.z), f2bf(f.w)};
  *(ushort4*)&out[i] = *(ushort4*)u;
}

// vg = v * illu (4 elems/thread)
__global__ void gate_kernel(const unsigned short* __restrict__ v,
                            const float* __restrict__ illu,
                            unsigned short* __restrict__ vg) {
  size_t i = ((size_t)blockIdx.x * 256 + threadIdx.x) * 4;
  ushort4 uv = *(const ushort4*)&v[i];
  float4 f = *(const float4*)&illu[i];
  unsigned short u[4] = {f2bf(bf2f(uv.x) * f.x), f2bf(bf2f(uv.y) * f.y),
                         f2bf(bf2f(uv.z) * f.z), f2bf(bf2f(uv.w) * f.w)};
  *(ushort4*)&vg[i] = *(ushort4*)u;
}

// ---------------------------------------------------------------------------
// Xt[b][c][n] = x_bf[b*16384+n][c]  (bf16 tile transpose, 64n x 32c tiles)
__global__ __launch_bounds__(256)
void transpose_x(const unsigned short* __restrict__ xb,
                 unsigned short* __restrict__ Xt) {
  // grid: (256 nblk, 16 cblk, 4 b)
  const int n0 = blockIdx.x * 64, c0 = blockIdx.y * 32, b = blockIdx.z;
  __shared__ unsigned short s[64][33];
  const int t = threadIdx.x;
  const int nr = t >> 3, c4 = (t & 7) * 4;   // in: rows nr, nr+32; cols c4..c4+3
#pragma unroll
  for (int half = 0; half < 2; ++half) {
    int n = nr + half * 32;
    ushort4 v = *(const ushort4*)&xb[((size_t)b * NTOK + n0 + n) * 512 + c0 + c4];
    s[n][c4] = v.x; s[n][c4 + 1] = v.y; s[n][c4 + 2] = v.z; s[n][c4 + 3] = v.w;
  }
  __syncthreads();
  const int n4 = (t & 15) * 4;               // out: rows cr, cr+16; cols n4..n4+3
#pragma unroll
  for (int half = 0; half < 2; ++half) {
    int cr = (t >> 4) + half * 16;
    unsigned short o[4] = {s[n4][cr], s[n4 + 1][cr], s[n4 + 2][cr], s[n4 + 3][cr]};
    *(ushort4*)&Xt[((size_t)b * 512 + c0 + cr) * 16384 + n0 + n4] = *(ushort4*)o;
  }
}

// ---------------------------------------------------------------------------
// C[M,512] = A[M,512] @ Bt[512,512]^T  (bf16 MFMA; fp32 accumulate)
// Barrier-free: NO LDS staging -- B is L2-resident (512KB), A-fragments are
// 16 rows x 64B contiguous segments; both load global->VGPR directly. The
// K-loop has zero barriers so loads pipeline freely across K-steps.
// XCD-aware remap: the 4 n-blocks sharing an A-tile run consecutively on one
// XCD (assumes dispatch xcd = bid % 8; perf heuristic only).
// MODE 0: store bf16. MODE 1: batched Bt (per 16384 rows), += bp[n]+outp[m,n],
// store fp32 (final output). Grid: dim3(4, M/128), gridDim.y % 8 == 0.
template <int MODE>
__global__ __launch_bounds__(256)
void gemm_bt(const unsigned short* __restrict__ A,
             const unsigned short* __restrict__ Bt,
             void* __restrict__ Cv,
             const float* __restrict__ bp,
             const unsigned short* __restrict__ outp) {
  const int tid = threadIdx.x;
  const int bid = blockIdx.y * 4 + blockIdx.x;
  const int mpx = gridDim.y >> 3;        // m-tiles per xcd
  const int xcd = bid & 7;
  const int loc = bid >> 3;
  const int m0 = (xcd * mpx + (loc >> 2)) * 128;
  const int n0 = (loc & 3) * 128;
  if (MODE == 1) Bt += (size_t)(m0 >> 14) * (512 * 512);  // per-batch B
  const int w = tid >> 6;
  const int lane = tid & 63;
  const int wr = (w >> 1) * 64;   // wave row offset in tile
  const int wc = (w & 1) * 64;    // wave col offset in tile
  const int lrow = lane & 15;
  const int quad = lane >> 4;

  f32x4 acc[4][4];
#pragma unroll
  for (int i = 0; i < 4; ++i)
#pragma unroll
    for (int j = 0; j < 4; ++j) acc[i][j] = (f32x4)(0.0f);

  const unsigned short* Ab = A + (size_t)(m0 + wr + lrow) * 512 + quad * 8;
  const unsigned short* Bb = Bt + (size_t)(n0 + wc + lrow) * 512 + quad * 8;

#pragma unroll 2
  for (int k0 = 0; k0 < 512; k0 += 32) {
    s16x8 af[4], bfr[4];
#pragma unroll
    for (int i = 0; i < 4; ++i)
      af[i] = *(const s16x8*)(Ab + (size_t)(i * 16) * 512 + k0);
#pragma unroll
    for (int j = 0; j < 4; ++j)
      bfr[j] = *(const s16x8*)(Bb + (size_t)(j * 16) * 512 + k0);
#pragma unroll
    for (int i = 0; i < 4; ++i)
#pragma unroll
      for (int j = 0; j < 4; ++j)
        acc[i][j] = __builtin_amdgcn_mfma_f32_16x16x32_bf16(af[i], bfr[j],
                                                            acc[i][j], 0, 0, 0);
  }

#pragma unroll
  for (int i = 0; i < 4; ++i)
#pragma unroll
    for (int j = 0; j < 4; ++j)
#pragma unroll
      for (int rg = 0; rg < 4; ++rg) {
        int row = wr + i * 16 + quad * 4 + rg;   // C/D: row=(lane>>4)*4+reg
        int col = wc + j * 16 + lrow;            //      col=lane&15
        size_t m = (size_t)(m0 + row);
        int n = n0 + col;
        float v = acc[i][j][rg];
        if (MODE == 1) {
          ((float*)Cv)[m * 512 + n] = v + bp[n] + bf2f(outp[m * 512 + n]);
        } else {
          ((unsigned short*)Cv)[m * 512 + n] = f2bf(v);
        }
      }
}

// ---------------------------------------------------------------------------
// G_b += Xt_b[m-tile] @ Xt_b[n-tile]^T over a K-chunk (K total = 16384).
// Symmetric: only tiles mi>=nj computed; mirror_g fills the rest.
// Barrier-free direct-global fragments (same rationale as gemm_bt); fp32
// atomic epilogue into G[4][512][512].
__global__ __launch_bounds__(256)
void gram_kernel(const unsigned short* __restrict__ Xt,
                 float* __restrict__ G) {
  static const int MI[10] = {0, 1, 1, 2, 2, 2, 3, 3, 3, 3};
  static const int NJ[10] = {0, 0, 1, 0, 1, 2, 0, 1, 2, 3};
  const int tid = threadIdx.x;
  const int ti = blockIdx.x;       // 0..9
  const int b = blockIdx.y;        // 0..3
  const int kc = blockIdx.z;       // 0..7 (2048-wide K chunks)
  const int m0 = MI[ti] * 128;
  const int n0 = NJ[ti] * 128;
  const unsigned short* Xb = Xt + (size_t)b * 512 * 16384;
  const int w = tid >> 6;
  const int lane = tid & 63;
  const int wr = (w >> 1) * 64;
  const int wc = (w & 1) * 64;
  const int lrow = lane & 15;
  const int quad = lane >> 4;

  f32x4 acc[4][4];
#pragma unroll
  for (int i = 0; i < 4; ++i)
#pragma unroll
    for (int j = 0; j < 4; ++j) acc[i][j] = (f32x4)(0.0f);

  const unsigned short* Ab = Xb + (size_t)(m0 + wr + lrow) * 16384 + quad * 8;
  const unsigned short* Bb = Xb + (size_t)(n0 + wc + lrow) * 16384 + quad * 8;

  const int kend = kc * 2048 + 2048;
#pragma unroll 2
  for (int k0 = kc * 2048; k0 < kend; k0 += 32) {
    s16x8 af[4], bfr[4];
#pragma unroll
    for (int i = 0; i < 4; ++i)
      af[i] = *(const s16x8*)(Ab + (size_t)(i * 16) * 16384 + k0);
#pragma unroll
    for (int j = 0; j < 4; ++j)
      bfr[j] = *(const s16x8*)(Bb + (size_t)(j * 16) * 16384 + k0);
#pragma unroll
    for (int i = 0; i < 4; ++i)
#pragma unroll
      for (int j = 0; j < 4; ++j)
        acc[i][j] = __builtin_amdgcn_mfma_f32_16x16x32_bf16(af[i], bfr[j],
                                                            acc[i][j], 0, 0, 0);
  }

  float* Gp = G + (size_t)b * 512 * 512;
#pragma unroll
  for (int i = 0; i < 4; ++i)
#pragma unroll
    for (int j = 0; j < 4; ++j)
#pragma unroll
      for (int rg = 0; rg < 4; ++rg) {
        int row = m0 + wr + i * 16 + quad * 4 + rg;
        int col = n0 + wc + j * 16 + lrow;
        atomicAdd(&Gp[(size_t)row * 512 + col], acc[i][j][rg]);
      }
}

// fill upper-triangle tiles of G by symmetry
__global__ void mirror_g(float* __restrict__ G) {
  static const int MIu[6] = {0, 0, 0, 1, 1, 2};
  static const int NJu[6] = {1, 2, 3, 2, 3, 3};
  int ti = blockIdx.x % 6, b = blockIdx.x / 6;
  int r0 = MIu[ti] * 128, c0 = NJu[ti] * 128;
  float* Gb = G + (size_t)b * 512 * 512;
  for (int e = threadIdx.x; e < 128 * 128; e += 256) {
    int rr = e >> 7, cc = e & 127;
    Gb[(size_t)(r0 + rr) * 512 + c0 + cc] = Gb[(size_t)(c0 + cc) * 512 + r0 + rr];
  }
}

// ---------------------------------------------------------------------------
// S[b,h,d,e] = sum_c Wk[c, h*64+d] * Tq[b*512+c, h*64+e]   (one block per bh)
__global__ __launch_bounds__(256)
void score512_kernel(const float* __restrict__ Wk,
                     const unsigned short* __restrict__ Tq,
                     float* __restrict__ S) {
  int bh = blockIdx.x, b = bh >> 3, h = bh & 7;
  __shared__ float sK[16 * 64], sQ[16 * 64];
  int tid = threadIdx.x;
  int ty = tid >> 4, tx = tid & 15;
  float acc[4][4] = {};
  const int srr = tid >> 4;          // staging row (0..15)
  const int scc = (tid & 15) * 4;    // staging col (0..60)
  for (int c0 = 0; c0 < 512; c0 += 16) {
    __syncthreads();
    {
      float4 wv = *(const float4*)&Wk[(size_t)(c0 + srr) * 512 + h * 64 + scc];
      ushort4 uq = *(const ushort4*)&Tq[((size_t)b * 512 + c0 + srr) * 512 + h * 64 + scc];
      *(float4*)&sK[srr * 64 + scc] = wv;
      *(float4*)&sQ[srr * 64 + scc] =
          make_float4(bf2f(uq.x), bf2f(uq.y), bf2f(uq.z), bf2f(uq.w));
    }
    __syncthreads();
#pragma unroll
    for (int nn = 0; nn < 16; ++nn) {
      float4 kv = *(float4*)&sK[nn * 64 + ty * 4];
      float4 qv = *(float4*)&sQ[nn * 64 + tx * 4];
      float kr[4] = {kv.x, kv.y, kv.z, kv.w};
      float qr[4] = {qv.x, qv.y, qv.z, qv.w};
#pragma unroll
      for (int rr = 0; rr < 4; ++rr)
#pragma unroll
        for (int cc = 0; cc < 4; ++cc) acc[rr][cc] += kr[rr] * qr[cc];
    }
  }
  float* Sp = S + (size_t)bh * 64 * 64;
#pragma unroll
  for (int rr = 0; rr < 4; ++rr)
#pragma unroll
    for (int cc = 0; cc < 4; ++cc)
      Sp[(ty * 4 + rr) * 64 + tx * 4 + cc] = acc[rr][cc];
}

// ---------------------------------------------------------------------------
// raw norms: inv[t][b][c] += sum_{c' in 64-chunk} W[c'][c] * T[b*512+c'][c]
// (t=0: Wq/Tq, t=1: Wk/Tk). 64 blocks (was 8 -- latency-starved on 256 CUs).
// inv must be zeroed. inv_norm_kernel then maps to 1/max(sqrt,eps).
__global__ __launch_bounds__(256)
void norm_dot_kernel(const float* __restrict__ Wq, const float* __restrict__ Wk,
                     const unsigned short* __restrict__ Tq,
                     const unsigned short* __restrict__ Tk,
                     float* __restrict__ inv) {
  int g = blockIdx.x;              // 64 = t(2) * b(4) * cc(8)
  int t = g >> 5, b = (g >> 3) & 3, cc = g & 7;
  const float* W = t ? Wk : Wq;
  const unsigned short* T = t ? Tk : Tq;
  float* dst = inv + t * 2048 + b * 512;
  int tid = threadIdx.x;
  float a0 = 0.f, a1 = 0.f;
  for (int c = cc * 64; c < cc * 64 + 64; ++c) {
    const float* wr = W + (size_t)c * 512;
    const unsigned short* tr = T + ((size_t)b * 512 + c) * 512;
    a0 += wr[tid] * bf2f(tr[tid]);
    a1 += wr[tid + 256] * bf2f(tr[tid + 256]);
  }
  atomicAdd(&dst[tid], a0);
  atomicAdd(&dst[tid + 256], a1);
}

__global__ void inv_norm_kernel(float* s) {
  int i = blockIdx.x * 256 + threadIdx.x;   // 4096 total
  s[i] = 1.f / fmaxf(sqrtf(s[i]), 1e-12f);
}

// ---------------------------------------------------------------------------
// softmax over e with normalization scales folded in. One wave per (b,h,d).
__global__ void softmax_kernel(float* __restrict__ S,
                               const float* __restrict__ inv,
                               const float* __restrict__ rescale) {
  int row = blockIdx.x;            // bh*64 + d
  int bh = row >> 6, d = row & 63;
  int b = bh >> 3, h = bh & 7;
  int e = threadIdx.x;
  const float* invq = inv;         // [4][512]
  const float* invk = inv + 2048;
  float v = S[(size_t)row * 64 + e] * invk[b * 512 + h * 64 + d] *
            invq[b * 512 + h * 64 + e] * rescale[h];
  float m = v;
#pragma unroll
  for (int off = 32; off; off >>= 1) m = fmaxf(m, __shfl_xor(m, off));
  float ex = expf(v - m);
  float s = ex;
#pragma unroll
  for (int off = 32; off; off >>= 1) s += __shfl_xor(s, off);
  S[(size_t)row * 64 + e] = ex / s;
}

// ---------------------------------------------------------------------------
// M2T[b][n][h*64+e] = sum_d attn[b,h,d,e] * WpT[n][h*64+d]  (bf16 out)
// Folds attention into the output projection: out_c = Vg @ M2T^T.
__global__ __launch_bounds__(256)
void combine_kernel(const float* __restrict__ S,
                    const unsigned short* __restrict__ WpT,
                    unsigned short* __restrict__ M2T) {
  int bn = blockIdx.x;
  int b = bn >> 9, n = bn & 511;
  int tid = threadIdx.x;
  __shared__ float sW[512];
  sW[tid] = bf2f(WpT[n * 512 + tid]);
  sW[tid + 256] = bf2f(WpT[n * 512 + tid + 256]);
  __syncthreads();
#pragma unroll
  for (int cc = 0; cc < 2; ++cc) {
    int c = tid + cc * 256;
    int h = c >> 6, e = c & 63;
    const float* ap = S + ((size_t)(b * 8 + h) * 64) * 64 + e;  // + d*64
    float acc = 0.f;
#pragma unroll
    for (int d = 0; d < 64; ++d) acc += ap[d * 64] * sW[h * 64 + d];
    M2T[((size_t)bn) * 512 + c] = f2bf(acc);
  }
}

// ---------------------------------------------------------------------------
// FUSED depthwise 3x3 -> GELU(exact) -> depthwise 3x3, SAME pad, NHWC bf16.
__global__ __launch_bounds__(256)
void dwconv_fused_kernel(const unsigned short* __restrict__ in,
                         const float* __restrict__ w1g,
                         const float* __restrict__ w2g,
                         unsigned short* __restrict__ out) {
  // grid.x = b(4) * cblk(64) * ytile(8)
  const int bid = blockIdx.x;
  const int yt = bid & 7;
  const int cb = (bid >> 3) & 63;
  const int b  = bid >> 9;
  const int tid = threadIdx.x;
  const int x  = tid >> 1;        // 0..127
  const int cg = tid & 1;         // channel group of 4
  const int c  = cb * 8 + cg * 4; // first channel of this thread
  const int y0 = yt * 16;

  // rings: [slot 3][pos 130][ch 8] bf16; pos 0 and 129 are zero pad (x=-1,128)
  __shared__ short inr[3 * 1040];
  __shared__ short c1r[3 * 1040];

  if (tid < 12) {  // zero the pad columns once (2 rings x 3 slots x 2 pos)
    int pos = (tid & 1) ? 129 : 0;
    int slot = (tid >> 1) % 3;
    short* basep = (tid >= 6) ? c1r : inr;
    unsigned short z[4] = {0, 0, 0, 0};
    *(ushort4*)&basep[slot * 1040 + pos * 8] = *(ushort4*)z;
    *(ushort4*)&basep[slot * 1040 + pos * 8 + 4] = *(ushort4*)z;
  }

  float w1[4][9], w2[4][9];
#pragma unroll
  for (int j = 0; j < 4; ++j)
#pragma unroll
    for (int k = 0; k < 9; ++k) {
      w1[j][k] = w1g[(c + j) * 9 + k];
      w2[j][k] = w2g[(c + j) * 9 + k];
    }

  const size_t inbase = ((size_t)b * NTOK) * 512 + c;  // + (y*128+x)*512

  for (int it = 0; it < 20; ++it) {
    const int L = y0 - 2 + it;
    unsigned short rin[4] = {0, 0, 0, 0};
    if (L >= 0 && L <= 127)
      *(ushort4*)rin = *(const ushort4*)&in[inbase + ((size_t)(L * 128 + x) << 9)];
    *(ushort4*)&inr[((L + 3) % 3) * 1040 + (x + 1) * 8 + cg * 4] = *(ushort4*)rin;
    __syncthreads();

    if (it >= 2) {
      const int R = L - 1;
      float cv[4] = {0.f, 0.f, 0.f, 0.f};
      if (R >= 0 && R <= 127) {
#pragma unroll
        for (int ky = 0; ky < 3; ++ky) {
          const short* rp = &inr[((R - 1 + ky + 3) % 3) * 1040 + x * 8 + cg * 4];
#pragma unroll
          for (int kx = 0; kx < 3; ++kx) {
            unsigned short u[4];
            *(ushort4*)u = *(const ushort4*)&rp[kx * 8];
#pragma unroll
            for (int j = 0; j < 4; ++j)
              cv[j] += w1[j][ky * 3 + kx] * bf2f(u[j]);
          }
        }
#pragma unroll
        for (int j = 0; j < 4; ++j)
          cv[j] = 0.5f * cv[j] * (1.f + erff(cv[j] * 0.70710678118654752f));
      }
      unsigned short rc[4] = {f2bf(cv[0]), f2bf(cv[1]), f2bf(cv[2]), f2bf(cv[3])};
      *(ushort4*)&c1r[((R + 3) % 3) * 1040 + (x + 1) * 8 + cg * 4] = *(ushort4*)rc;
    }
    __syncthreads();

    if (it >= 4) {
      const int O = L - 2;
      float av[4] = {0.f, 0.f, 0.f, 0.f};
#pragma unroll
      for (int ky = 0; ky < 3; ++ky) {
        const short* rp = &c1r[((O - 1 + ky + 3) % 3) * 1040 + x * 8 + cg * 4];
#pragma unroll
        for (int kx = 0; kx < 3; ++kx) {
          unsigned short u[4];
          *(ushort4*)u = *(const ushort4*)&rp[kx * 8];
#pragma unroll
          for (int j = 0; j < 4; ++j)
            av[j] += w2[j][ky * 3 + kx] * bf2f(u[j]);
        }
      }
      unsigned short ro[4] = {f2bf(av[0]), f2bf(av[1]), f2bf(av[2]), f2bf(av[3])};
      *(ushort4*)&out[inbase + ((size_t)(O * 128 + x) << 9)] = *(ushort4*)ro;
    }
  }
}

// ---------------------------------------------------------------------------
extern "C" void kernel_launch(void* const* d_in, const int* in_sizes, int n_in,
                              void* d_out, int out_size, void* d_ws,
                              size_t ws_size, hipStream_t stream) {
  const float* x    = (const float*)d_in[0];
  const float* illu = (const float*)d_in[1];
  const float* Wq   = (const float*)d_in[2];
  const float* Wk   = (const float*)d_in[3];
  const float* Wv   = (const float*)d_in[4];
  const float* resc = (const float*)d_in[5];
  const float* Wp   = (const float*)d_in[6];
  const float* bp   = (const float*)d_in[7];
  const float* c1w  = (const float*)d_in[8];
  const float* c2w  = (const float*)d_in[9];
  float* out = (float*)d_out;

  char* ws = (char*)d_ws;
  const size_t SZ = (size_t)MROWS * 512 * sizeof(unsigned short);  // 64 MiB
  // ws0: Xt (transpose->gram), then G_bf/Tq/Tk after gram
  unsigned short* Xt   = (unsigned short*)(ws);
  unsigned short* G_bf = (unsigned short*)(ws);                 // 2 MiB
  unsigned short* Tq   = (unsigned short*)(ws + 2 * 1024 * 1024);
  unsigned short* Tk   = (unsigned short*)(ws + 4 * 1024 * 1024);
  // ws1: G (fp32, 4 MiB, head of slot) then dwconv output (whole slot)
  float*          G    = (float*)(ws + SZ);
  unsigned short* outp = (unsigned short*)(ws + SZ);
  unsigned short* v_ws = (unsigned short*)(ws + 2 * SZ);
  unsigned short* x_bf = (unsigned short*)(ws + 3 * SZ);  // later: vg
  unsigned short* WqT = (unsigned short*)(ws + 4 * SZ);
  unsigned short* WkT = WqT + 512 * 512;
  unsigned short* WvT = WkT + 512 * 512;
  unsigned short* WpT = WvT + 512 * 512;
  unsigned short* M2T = WpT + 512 * 512;    // [4][512][512] bf16
  float* S   = (float*)(M2T + 4 * 512 * 512);   // [4][8][64][64]
  float* inv = S + 4 * 8 * 64 * 64;             // [2][4][512]

  transpose512<<<1024, 256, 0, stream>>>(Wq, WqT);
  transpose512<<<1024, 256, 0, stream>>>(Wk, WkT);
  transpose512<<<1024, 256, 0, stream>>>(Wv, WvT);
  transpose512<<<1024, 256, 0, stream>>>(Wp, WpT);
  convert_bf16<<<32768, 256, 0, stream>>>(x, x_bf);
  hipMemsetAsync(G, 0, (size_t)4 * 512 * 512 * sizeof(float), stream);
  hipMemsetAsync(inv, 0, (size_t)4096 * sizeof(float), stream);

  // V projection (bf16 in -> bf16 out)
  gemm_bt<0><<<dim3(4, 512), 256, 0, stream>>>(x_bf, WvT, v_ws, nullptr, nullptr);

  // Gram path: Xt = x_bf^T per batch; G = Xt Xt^T (lower tiles) ; mirror
  transpose_x<<<dim3(256, 16, 4), 256, 0, stream>>>(x_bf, Xt);
  gram_kernel<<<dim3(10, 4, 8), 256, 0, stream>>>(Xt, G);
  mirror_g<<<24, 256, 0, stream>>>(G);
  // G -> bf16 (1M floats, 4/thread)
  convert_bf16<<<1024, 256, 0, stream>>>(G, G_bf);

  // Tq = G @ Wq, Tk = G @ Wk  (per batch; M=2048 stacked)
  gemm_bt<0><<<dim3(4, 16), 256, 0, stream>>>(G_bf, WqT, Tq, nullptr, nullptr);
  gemm_bt<0><<<dim3(4, 16), 256, 0, stream>>>(G_bf, WkT, Tk, nullptr, nullptr);

  // S = Wk_h^T (G Wq_h); norms = diag(W^T G W); then softmax
  score512_kernel<<<32, 256, 0, stream>>>(Wk, Tq, S);
  norm_dot_kernel<<<64, 256, 0, stream>>>(Wq, Wk, Tq, Tk, inv);
  inv_norm_kernel<<<16, 256, 0, stream>>>(inv);
  softmax_kernel<<<2048, 64, 0, stream>>>(S, inv, resc);

  // fold attention into output projection
  combine_kernel<<<2048, 256, 0, stream>>>(S, WpT, M2T);

  // gated values (x_bf dead after V-gemm/transpose -> reuse as vg)
  gate_kernel<<<32768, 256, 0, stream>>>(v_ws, illu, x_bf);

  // positional branch: fused dwconv->GELU->dwconv (overwrites G region; G dead)
  dwconv_fused_kernel<<<2048, 256, 0, stream>>>(v_ws, c1w, c2w, outp);

  // out = Vg @ M2T^T + bp + out_p  (fp32 output)
  gemm_bt<1><<<dim3(4, 512), 256, 0, stream>>>(x_bf, M2T, out, bp, outp);
}

// Round 4
// 749.408 us; speedup vs baseline: 1.2402x; 1.2402x over previous
//
#include <hip/hip_runtime.h>
#include <hip/hip_bf16.h>

typedef short s16x8 __attribute__((ext_vector_type(8)));
typedef float f32x4 __attribute__((ext_vector_type(4)));

#define NTOK 16384           // H*W per batch
#define MROWS 65536          // b * NTOK

__device__ __forceinline__ float bf2f(unsigned short u) {
  union { unsigned int i; float f; } v; v.i = ((unsigned int)u) << 16; return v.f;
}
__device__ __forceinline__ unsigned short f2bf(float f) {
  union { float f; unsigned int i; } v; v.f = f;
  unsigned int x = v.i;
  return (unsigned short)((x + 0x7fffu + ((x >> 16) & 1u)) >> 16);
}

// async global->LDS, 16B per lane. LDS dest must be wave-uniform base + lane*16.
__device__ __forceinline__ void async16(const unsigned short* g, short* l) {
  __builtin_amdgcn_global_load_lds(
      (__attribute__((address_space(1))) void*)(unsigned short*)g,
      (__attribute__((address_space(3))) void*)l, 16, 0, 0);
}

// ---------------------------------------------------------------------------
// Transpose+convert a 512x512 fp32 weight to bf16: Wt[n][k] = W[k][n]
__global__ void transpose512(const float* __restrict__ W,
                             unsigned short* __restrict__ Wt) {
  int idx = blockIdx.x * 256 + threadIdx.x;   // = n*512 + k
  int n = idx >> 9, k = idx & 511;
  Wt[idx] = f2bf(W[k * 512 + n]);
}

// fp32 -> bf16 bulk convert (4 elems/thread)
__global__ void convert_bf16(const float* __restrict__ in,
                             unsigned short* __restrict__ out) {
  size_t i = ((size_t)blockIdx.x * 256 + threadIdx.x) * 4;
  float4 f = *(const float4*)&in[i];
  unsigned short u[4] = {f2bf(f.x), f2bf(f.y), f2bf(f.z), f2bf(f.w)};
  *(ushort4*)&out[i] = *(ushort4*)u;
}

// vg = v * illu (4 elems/thread)
__global__ void gate_kernel(const unsigned short* __restrict__ v,
                            const float* __restrict__ illu,
                            unsigned short* __restrict__ vg) {
  size_t i = ((size_t)blockIdx.x * 256 + threadIdx.x) * 4;
  ushort4 uv = *(const ushort4*)&v[i];
  float4 f = *(const float4*)&illu[i];
  unsigned short u[4] = {f2bf(bf2f(uv.x) * f.x), f2bf(bf2f(uv.y) * f.y),
                         f2bf(bf2f(uv.z) * f.z), f2bf(bf2f(uv.w) * f.w)};
  *(ushort4*)&vg[i] = *(ushort4*)u;
}

// ---------------------------------------------------------------------------
// Xt[b][c][n] = x_bf[b*16384+n][c]  (bf16 tile transpose, 64n x 32c tiles)
__global__ __launch_bounds__(256)
void transpose_x(const unsigned short* __restrict__ xb,
                 unsigned short* __restrict__ Xt) {
  // grid: (256 nblk, 16 cblk, 4 b)
  const int n0 = blockIdx.x * 64, c0 = blockIdx.y * 32, b = blockIdx.z;
  __shared__ unsigned short s[64][33];
  const int t = threadIdx.x;
  const int nr = t >> 3, c4 = (t & 7) * 4;   // in: rows nr, nr+32; cols c4..c4+3
#pragma unroll
  for (int half = 0; half < 2; ++half) {
    int n = nr + half * 32;
    ushort4 v = *(const ushort4*)&xb[((size_t)b * NTOK + n0 + n) * 512 + c0 + c4];
    s[n][c4] = v.x; s[n][c4 + 1] = v.y; s[n][c4 + 2] = v.z; s[n][c4 + 3] = v.w;
  }
  __syncthreads();
  const int n4 = (t & 15) * 4;               // out: rows cr, cr+16; cols n4..n4+3
#pragma unroll
  for (int half = 0; half < 2; ++half) {
    int cr = (t >> 4) + half * 16;
    unsigned short o[4] = {s[n4][cr], s[n4 + 1][cr], s[n4 + 2][cr], s[n4 + 3][cr]};
    *(ushort4*)&Xt[((size_t)b * 512 + c0 + cr) * 16384 + n0 + n4] = *(ushort4*)o;
  }
}

// ---------------------------------------------------------------------------
// C[M,512] = A[M,512] @ Bt[512,512]^T  (bf16 MFMA; fp32 accumulate)
// LDS-staged (global_load_lds w16) + double-buffered: stage tile t+1 is
// issued BEFORE compute of tile t, so its HBM/L2 latency hides under the
// ds_read+MFMA work; one barrier per K-step (its implicit vmcnt(0) drains
// the prefetch). XCD-aware remap: the 4 n-blocks sharing an A-panel run on
// one XCD -> A is L2-hot (FETCH ~halved, drain is L2-latency not HBM).
// MODE 0: store bf16. MODE 1: batched Bt (per 16384 rows), += bp[n]+outp[m,n],
// store fp32 (final output). Grid: dim3(4, M/128), gridDim.y % 8 == 0.
template <int MODE>
__global__ __launch_bounds__(256)
void gemm_bt(const unsigned short* __restrict__ A,
             const unsigned short* __restrict__ Bt,
             void* __restrict__ Cv,
             const float* __restrict__ bp,
             const unsigned short* __restrict__ outp) {
  __shared__ short sA[2][128 * 32];
  __shared__ short sB[2][128 * 32];
  const int tid = threadIdx.x;
  const int bid = blockIdx.y * 4 + blockIdx.x;
  const int mpx = gridDim.y >> 3;        // m-tiles per xcd
  const int xcd = bid & 7;
  const int loc = bid >> 3;
  const int m0 = (xcd * mpx + (loc >> 2)) * 128;
  const int n0 = (loc & 3) * 128;
  if (MODE == 1) Bt += (size_t)(m0 >> 14) * (512 * 512);  // per-batch B
  const int w = tid >> 6;
  const int lane = tid & 63;
  const int wr = (w >> 1) * 64;   // wave row offset in tile
  const int wc = (w & 1) * 64;    // wave col offset in tile
  const int lrow = lane & 15;
  const int quad = lane >> 4;

  f32x4 acc[4][4];
#pragma unroll
  for (int i = 0; i < 4; ++i)
#pragma unroll
    for (int j = 0; j < 4; ++j) acc[i][j] = (f32x4)(0.0f);

  const int r = tid >> 2;          // 0..63
  const int c8 = (tid & 3) * 8;    // 0,8,16,24 (shorts)
  const unsigned short* Ar0 = A + (size_t)(m0 + r) * 512 + c8;
  const unsigned short* Ar1 = Ar0 + (size_t)64 * 512;
  const unsigned short* Br0 = Bt + (size_t)(n0 + r) * 512 + c8;
  const unsigned short* Br1 = Br0 + (size_t)64 * 512;

  // prologue: stage K-tile 0 into buffer 0
  async16(Ar0, &sA[0][tid * 8]);
  async16(Ar1, &sA[0][tid * 8 + 64 * 32]);
  async16(Br0, &sB[0][tid * 8]);
  async16(Br1, &sB[0][tid * 8 + 64 * 32]);
  __syncthreads();

  int cur = 0;
  for (int k0 = 0; k0 < 512; k0 += 32) {
    if (k0 + 32 < 512) {           // prefetch next K-tile into other buffer
      const int nxt = cur ^ 1;
      async16(Ar0 + k0 + 32, &sA[nxt][tid * 8]);
      async16(Ar1 + k0 + 32, &sA[nxt][tid * 8 + 64 * 32]);
      async16(Br0 + k0 + 32, &sB[nxt][tid * 8]);
      async16(Br1 + k0 + 32, &sB[nxt][tid * 8 + 64 * 32]);
    }
    s16x8 af[4], bfr[4];
#pragma unroll
    for (int i = 0; i < 4; ++i)
      af[i] = *(s16x8*)&sA[cur][(wr + i * 16 + lrow) * 32 + quad * 8];
#pragma unroll
    for (int j = 0; j < 4; ++j)
      bfr[j] = *(s16x8*)&sB[cur][(wc + j * 16 + lrow) * 32 + quad * 8];
#pragma unroll
    for (int i = 0; i < 4; ++i)
#pragma unroll
      for (int j = 0; j < 4; ++j)
        acc[i][j] = __builtin_amdgcn_mfma_f32_16x16x32_bf16(af[i], bfr[j],
                                                            acc[i][j], 0, 0, 0);
    __syncthreads();   // drains prefetch (vmcnt 0) + protects buffer swap
    cur ^= 1;
  }

#pragma unroll
  for (int i = 0; i < 4; ++i)
#pragma unroll
    for (int j = 0; j < 4; ++j)
#pragma unroll
      for (int rg = 0; rg < 4; ++rg) {
        int row = wr + i * 16 + quad * 4 + rg;   // C/D: row=(lane>>4)*4+reg
        int col = wc + j * 16 + lrow;            //      col=lane&15
        size_t m = (size_t)(m0 + row);
        int n = n0 + col;
        float v = acc[i][j][rg];
        if (MODE == 1) {
          ((float*)Cv)[m * 512 + n] = v + bp[n] + bf2f(outp[m * 512 + n]);
        } else {
          ((unsigned short*)Cv)[m * 512 + n] = f2bf(v);
        }
      }
}

// ---------------------------------------------------------------------------
// G_b += Xt_b[m-tile] @ Xt_b[n-tile]^T over a K-chunk (K total = 16384).
// Symmetric: only tiles mi>=nj computed; mirror_g fills the rest.
// Same LDS-dbuf structure as gemm_bt; fp32 atomic epilogue into G[4][512][512].
__global__ __launch_bounds__(256)
void gram_kernel(const unsigned short* __restrict__ Xt,
                 float* __restrict__ G) {
  static const int MI[10] = {0, 1, 1, 2, 2, 2, 3, 3, 3, 3};
  static const int NJ[10] = {0, 0, 1, 0, 1, 2, 0, 1, 2, 3};
  __shared__ short sA[2][128 * 32];
  __shared__ short sB[2][128 * 32];
  const int tid = threadIdx.x;
  const int ti = blockIdx.x;       // 0..9
  const int b = blockIdx.y;        // 0..3
  const int kc = blockIdx.z;       // 0..7 (2048-wide K chunks)
  const int m0 = MI[ti] * 128;
  const int n0 = NJ[ti] * 128;
  const unsigned short* Xb = Xt + (size_t)b * 512 * 16384;
  const int w = tid >> 6;
  const int lane = tid & 63;
  const int wr = (w >> 1) * 64;
  const int wc = (w & 1) * 64;
  const int lrow = lane & 15;
  const int quad = lane >> 4;

  f32x4 acc[4][4];
#pragma unroll
  for (int i = 0; i < 4; ++i)
#pragma unroll
    for (int j = 0; j < 4; ++j) acc[i][j] = (f32x4)(0.0f);

  const int r = tid >> 2;
  const int c8 = (tid & 3) * 8;
  const unsigned short* Ar0 = Xb + (size_t)(m0 + r) * 16384 + c8;
  const unsigned short* Ar1 = Ar0 + (size_t)64 * 16384;
  const unsigned short* Br0 = Xb + (size_t)(n0 + r) * 16384 + c8;
  const unsigned short* Br1 = Br0 + (size_t)64 * 16384;

  const int kbeg = kc * 2048, kend = kbeg + 2048;
  // prologue: stage first K-tile into buffer 0
  async16(Ar0 + kbeg, &sA[0][tid * 8]);
  async16(Ar1 + kbeg, &sA[0][tid * 8 + 64 * 32]);
  async16(Br0 + kbeg, &sB[0][tid * 8]);
  async16(Br1 + kbeg, &sB[0][tid * 8 + 64 * 32]);
  __syncthreads();

  int cur = 0;
  for (int k0 = kbeg; k0 < kend; k0 += 32) {
    if (k0 + 32 < kend) {
      const int nxt = cur ^ 1;
      async16(Ar0 + k0 + 32, &sA[nxt][tid * 8]);
      async16(Ar1 + k0 + 32, &sA[nxt][tid * 8 + 64 * 32]);
      async16(Br0 + k0 + 32, &sB[nxt][tid * 8]);
      async16(Br1 + k0 + 32, &sB[nxt][tid * 8 + 64 * 32]);
    }
    s16x8 af[4], bfr[4];
#pragma unroll
    for (int i = 0; i < 4; ++i)
      af[i] = *(s16x8*)&sA[cur][(wr + i * 16 + lrow) * 32 + quad * 8];
#pragma unroll
    for (int j = 0; j < 4; ++j)
      bfr[j] = *(s16x8*)&sB[cur][(wc + j * 16 + lrow) * 32 + quad * 8];
#pragma unroll
    for (int i = 0; i < 4; ++i)
#pragma unroll
      for (int j = 0; j < 4; ++j)
        acc[i][j] = __builtin_amdgcn_mfma_f32_16x16x32_bf16(af[i], bfr[j],
                                                            acc[i][j], 0, 0, 0);
    __syncthreads();
    cur ^= 1;
  }

  float* Gp = G + (size_t)b * 512 * 512;
#pragma unroll
  for (int i = 0; i < 4; ++i)
#pragma unroll
    for (int j = 0; j < 4; ++j)
#pragma unroll
      for (int rg = 0; rg < 4; ++rg) {
        int row = m0 + wr + i * 16 + quad * 4 + rg;
        int col = n0 + wc + j * 16 + lrow;
        atomicAdd(&Gp[(size_t)row * 512 + col], acc[i][j][rg]);
      }
}

// fill upper-triangle tiles of G by symmetry
__global__ void mirror_g(float* __restrict__ G) {
  static const int MIu[6] = {0, 0, 0, 1, 1, 2};
  static const int NJu[6] = {1, 2, 3, 2, 3, 3};
  int ti = blockIdx.x % 6, b = blockIdx.x / 6;
  int r0 = MIu[ti] * 128, c0 = NJu[ti] * 128;
  float* Gb = G + (size_t)b * 512 * 512;
  for (int e = threadIdx.x; e < 128 * 128; e += 256) {
    int rr = e >> 7, cc = e & 127;
    Gb[(size_t)(r0 + rr) * 512 + c0 + cc] = Gb[(size_t)(c0 + cc) * 512 + r0 + rr];
  }
}

// ---------------------------------------------------------------------------
// S[b,h,d,e] = sum_c Wk[c, h*64+d] * Tq[b*512+c, h*64+e]   (one block per bh)
__global__ __launch_bounds__(256)
void score512_kernel(const float* __restrict__ Wk,
                     const unsigned short* __restrict__ Tq,
                     float* __restrict__ S) {
  int bh = blockIdx.x, b = bh >> 3, h = bh & 7;
  __shared__ float sK[16 * 64], sQ[16 * 64];
  int tid = threadIdx.x;
  int ty = tid >> 4, tx = tid & 15;
  float acc[4][4] = {};
  const int srr = tid >> 4;          // staging row (0..15)
  const int scc = (tid & 15) * 4;    // staging col (0..60)
  for (int c0 = 0; c0 < 512; c0 += 16) {
    __syncthreads();
    {
      float4 wv = *(const float4*)&Wk[(size_t)(c0 + srr) * 512 + h * 64 + scc];
      ushort4 uq = *(const ushort4*)&Tq[((size_t)b * 512 + c0 + srr) * 512 + h * 64 + scc];
      *(float4*)&sK[srr * 64 + scc] = wv;
      *(float4*)&sQ[srr * 64 + scc] =
          make_float4(bf2f(uq.x), bf2f(uq.y), bf2f(uq.z), bf2f(uq.w));
    }
    __syncthreads();
#pragma unroll
    for (int nn = 0; nn < 16; ++nn) {
      float4 kv = *(float4*)&sK[nn * 64 + ty * 4];
      float4 qv = *(float4*)&sQ[nn * 64 + tx * 4];
      float kr[4] = {kv.x, kv.y, kv.z, kv.w};
      float qr[4] = {qv.x, qv.y, qv.z, qv.w};
#pragma unroll
      for (int rr = 0; rr < 4; ++rr)
#pragma unroll
        for (int cc = 0; cc < 4; ++cc) acc[rr][cc] += kr[rr] * qr[cc];
    }
  }
  float* Sp = S + (size_t)bh * 64 * 64;
#pragma unroll
  for (int rr = 0; rr < 4; ++rr)
#pragma unroll
    for (int cc = 0; cc < 4; ++cc)
      Sp[(ty * 4 + rr) * 64 + tx * 4 + cc] = acc[rr][cc];
}

// ---------------------------------------------------------------------------
// raw norms: inv[t][b][c] += sum_{c' in 64-chunk} W[c'][c] * T[b*512+c'][c]
// (t=0: Wq/Tq, t=1: Wk/Tk). 64 blocks; inv must be zeroed.
__global__ __launch_bounds__(256)
void norm_dot_kernel(const float* __restrict__ Wq, const float* __restrict__ Wk,
                     const unsigned short* __restrict__ Tq,
                     const unsigned short* __restrict__ Tk,
                     float* __restrict__ inv) {
  int g = blockIdx.x;              // 64 = t(2) * b(4) * cc(8)
  int t = g >> 5, b = (g >> 3) & 3, cc = g & 7;
  const float* W = t ? Wk : Wq;
  const unsigned short* T = t ? Tk : Tq;
  float* dst = inv + t * 2048 + b * 512;
  int tid = threadIdx.x;
  float a0 = 0.f, a1 = 0.f;
  for (int c = cc * 64; c < cc * 64 + 64; ++c) {
    const float* wr = W + (size_t)c * 512;
    const unsigned short* tr = T + ((size_t)b * 512 + c) * 512;
    a0 += wr[tid] * bf2f(tr[tid]);
    a1 += wr[tid + 256] * bf2f(tr[tid + 256]);
  }
  atomicAdd(&dst[tid], a0);
  atomicAdd(&dst[tid + 256], a1);
}

__global__ void inv_norm_kernel(float* s) {
  int i = blockIdx.x * 256 + threadIdx.x;   // 4096 total
  s[i] = 1.f / fmaxf(sqrtf(s[i]), 1e-12f);
}

// ---------------------------------------------------------------------------
// softmax over e with normalization scales folded in. One wave per (b,h,d).
__global__ void softmax_kernel(float* __restrict__ S,
                               const float* __restrict__ inv,
                               const float* __restrict__ rescale) {
  int row = blockIdx.x;            // bh*64 + d
  int bh = row >> 6, d = row & 63;
  int b = bh >> 3, h = bh & 7;
  int e = threadIdx.x;
  const float* invq = inv;         // [4][512]
  const float* invk = inv + 2048;
  float v = S[(size_t)row * 64 + e] * invk[b * 512 + h * 64 + d] *
            invq[b * 512 + h * 64 + e] * rescale[h];
  float m = v;
#pragma unroll
  for (int off = 32; off; off >>= 1) m = fmaxf(m, __shfl_xor(m, off));
  float ex = expf(v - m);
  float s = ex;
#pragma unroll
  for (int off = 32; off; off >>= 1) s += __shfl_xor(s, off);
  S[(size_t)row * 64 + e] = ex / s;
}

// ---------------------------------------------------------------------------
// M2T[b][n][h*64+e] = sum_d attn[b,h,d,e] * WpT[n][h*64+d]  (bf16 out)
// Folds attention into the output projection: out_c = Vg @ M2T^T.
__global__ __launch_bounds__(256)
void combine_kernel(const float* __restrict__ S,
                    const unsigned short* __restrict__ WpT,
                    unsigned short* __restrict__ M2T) {
  int bn = blockIdx.x;
  int b = bn >> 9, n = bn & 511;
  int tid = threadIdx.x;
  __shared__ float sW[512];
  sW[tid] = bf2f(WpT[n * 512 + tid]);
  sW[tid + 256] = bf2f(WpT[n * 512 + tid + 256]);
  __syncthreads();
#pragma unroll
  for (int cc = 0; cc < 2; ++cc) {
    int c = tid + cc * 256;
    int h = c >> 6, e = c & 63;
    const float* ap = S + ((size_t)(b * 8 + h) * 64) * 64 + e;  // + d*64
    float acc = 0.f;
#pragma unroll
    for (int d = 0; d < 64; ++d) acc += ap[d * 64] * sW[h * 64 + d];
    M2T[((size_t)bn) * 512 + c] = f2bf(acc);
  }
}

// ---------------------------------------------------------------------------
// FUSED depthwise 3x3 -> GELU(exact) -> depthwise 3x3, SAME pad, NHWC bf16.
__global__ __launch_bounds__(256)
void dwconv_fused_kernel(const unsigned short* __restrict__ in,
                         const float* __restrict__ w1g,
                         const float* __restrict__ w2g,
                         unsigned short* __restrict__ out) {
  // grid.x = b(4) * cblk(64) * ytile(8)
  const int bid = blockIdx.x;
  const int yt = bid & 7;
  const int cb = (bid >> 3) & 63;
  const int b  = bid >> 9;
  const int tid = threadIdx.x;
  const int x  = tid >> 1;        // 0..127
  const int cg = tid & 1;         // channel group of 4
  const int c  = cb * 8 + cg * 4; // first channel of this thread
  const int y0 = yt * 16;

  // rings: [slot 3][pos 130][ch 8] bf16; pos 0 and 129 are zero pad (x=-1,128)
  __shared__ short inr[3 * 1040];
  __shared__ short c1r[3 * 1040];

  if (tid < 12) {  // zero the pad columns once (2 rings x 3 slots x 2 pos)
    int pos = (tid & 1) ? 129 : 0;
    int slot = (tid >> 1) % 3;
    short* basep = (tid >= 6) ? c1r : inr;
    unsigned short z[4] = {0, 0, 0, 0};
    *(ushort4*)&basep[slot * 1040 + pos * 8] = *(ushort4*)z;
    *(ushort4*)&basep[slot * 1040 + pos * 8 + 4] = *(ushort4*)z;
  }

  float w1[4][9], w2[4][9];
#pragma unroll
  for (int j = 0; j < 4; ++j)
#pragma unroll
    for (int k = 0; k < 9; ++k) {
      w1[j][k] = w1g[(c + j) * 9 + k];
      w2[j][k] = w2g[(c + j) * 9 + k];
    }

  const size_t inbase = ((size_t)b * NTOK) * 512 + c;  // + (y*128+x)*512

  for (int it = 0; it < 20; ++it) {
    const int L = y0 - 2 + it;
    unsigned short rin[4] = {0, 0, 0, 0};
    if (L >= 0 && L <= 127)
      *(ushort4*)rin = *(const ushort4*)&in[inbase + ((size_t)(L * 128 + x) << 9)];
    *(ushort4*)&inr[((L + 3) % 3) * 1040 + (x + 1) * 8 + cg * 4] = *(ushort4*)rin;
    __syncthreads();

    if (it >= 2) {
      const int R = L - 1;
      float cv[4] = {0.f, 0.f, 0.f, 0.f};
      if (R >= 0 && R <= 127) {
#pragma unroll
        for (int ky = 0; ky < 3; ++ky) {
          const short* rp = &inr[((R - 1 + ky + 3) % 3) * 1040 + x * 8 + cg * 4];
#pragma unroll
          for (int kx = 0; kx < 3; ++kx) {
            unsigned short u[4];
            *(ushort4*)u = *(const ushort4*)&rp[kx * 8];
#pragma unroll
            for (int j = 0; j < 4; ++j)
              cv[j] += w1[j][ky * 3 + kx] * bf2f(u[j]);
          }
        }
#pragma unroll
        for (int j = 0; j < 4; ++j)
          cv[j] = 0.5f * cv[j] * (1.f + erff(cv[j] * 0.70710678118654752f));
      }
      unsigned short rc[4] = {f2bf(cv[0]), f2bf(cv[1]), f2bf(cv[2]), f2bf(cv[3])};
      *(ushort4*)&c1r[((R + 3) % 3) * 1040 + (x + 1) * 8 + cg * 4] = *(ushort4*)rc;
    }
    __syncthreads();

    if (it >= 4) {
      const int O = L - 2;
      float av[4] = {0.f, 0.f, 0.f, 0.f};
#pragma unroll
      for (int ky = 0; ky < 3; ++ky) {
        const short* rp = &c1r[((O - 1 + ky + 3) % 3) * 1040 + x * 8 + cg * 4];
#pragma unroll
        for (int kx = 0; kx < 3; ++kx) {
          unsigned short u[4];
          *(ushort4*)u = *(const ushort4*)&rp[kx * 8];
#pragma unroll
          for (int j = 0; j < 4; ++j)
            av[j] += w2[j][ky * 3 + kx] * bf2f(u[j]);
        }
      }
      unsigned short ro[4] = {f2bf(av[0]), f2bf(av[1]), f2bf(av[2]), f2bf(av[3])};
      *(ushort4*)&out[inbase + ((size_t)(O * 128 + x) << 9)] = *(ushort4*)ro;
    }
  }
}

// ---------------------------------------------------------------------------
extern "C" void kernel_launch(void* const* d_in, const int* in_sizes, int n_in,
                              void* d_out, int out_size, void* d_ws,
                              size_t ws_size, hipStream_t stream) {
  const float* x    = (const float*)d_in[0];
  const float* illu = (const float*)d_in[1];
  const float* Wq   = (const float*)d_in[2];
  const float* Wk   = (const float*)d_in[3];
  const float* Wv   = (const float*)d_in[4];
  const float* resc = (const float*)d_in[5];
  const float* Wp   = (const float*)d_in[6];
  const float* bp   = (const float*)d_in[7];
  const float* c1w  = (const float*)d_in[8];
  const float* c2w  = (const float*)d_in[9];
  float* out = (float*)d_out;

  char* ws = (char*)d_ws;
  const size_t SZ = (size_t)MROWS * 512 * sizeof(unsigned short);  // 64 MiB
  // ws0: Xt (transpose->gram), then G_bf/Tq/Tk after gram
  unsigned short* Xt   = (unsigned short*)(ws);
  unsigned short* G_bf = (unsigned short*)(ws);                 // 2 MiB
  unsigned short* Tq   = (unsigned short*)(ws + 2 * 1024 * 1024);
  unsigned short* Tk   = (unsigned short*)(ws + 4 * 1024 * 1024);
  // ws1: G (fp32, 4 MiB, head of slot) then dwconv output (whole slot)
  float*          G    = (float*)(ws + SZ);
  unsigned short* outp = (unsigned short*)(ws + SZ);
  unsigned short* v_ws = (unsigned short*)(ws + 2 * SZ);
  unsigned short* x_bf = (unsigned short*)(ws + 3 * SZ);  // later: vg
  unsigned short* WqT = (unsigned short*)(ws + 4 * SZ);
  unsigned short* WkT = WqT + 512 * 512;
  unsigned short* WvT = WkT + 512 * 512;
  unsigned short* WpT = WvT + 512 * 512;
  unsigned short* M2T = WpT + 512 * 512;    // [4][512][512] bf16
  float* S   = (float*)(M2T + 4 * 512 * 512);   // [4][8][64][64]
  float* inv = S + 4 * 8 * 64 * 64;             // [2][4][512]

  transpose512<<<1024, 256, 0, stream>>>(Wq, WqT);
  transpose512<<<1024, 256, 0, stream>>>(Wk, WkT);
  transpose512<<<1024, 256, 0, stream>>>(Wv, WvT);
  transpose512<<<1024, 256, 0, stream>>>(Wp, WpT);
  convert_bf16<<<32768, 256, 0, stream>>>(x, x_bf);
  hipMemsetAsync(G, 0, (size_t)4 * 512 * 512 * sizeof(float), stream);
  hipMemsetAsync(inv, 0, (size_t)4096 * sizeof(float), stream);

  // V projection (bf16 in -> bf16 out)
  gemm_bt<0><<<dim3(4, 512), 256, 0, stream>>>(x_bf, WvT, v_ws, nullptr, nullptr);

  // Gram path: Xt = x_bf^T per batch; G = Xt Xt^T (lower tiles) ; mirror
  transpose_x<<<dim3(256, 16, 4), 256, 0, stream>>>(x_bf, Xt);
  gram_kernel<<<dim3(10, 4, 8), 256, 0, stream>>>(Xt, G);
  mirror_g<<<24, 256, 0, stream>>>(G);
  // G -> bf16 (1M floats, 4/thread)
  convert_bf16<<<1024, 256, 0, stream>>>(G, G_bf);

  // Tq = G @ Wq, Tk = G @ Wk  (per batch; M=2048 stacked)
  gemm_bt<0><<<dim3(4, 16), 256, 0, stream>>>(G_bf, WqT, Tq, nullptr, nullptr);
  gemm_bt<0><<<dim3(4, 16), 256, 0, stream>>>(G_bf, WkT, Tk, nullptr, nullptr);

  // S = Wk_h^T (G Wq_h); norms = diag(W^T G W); then softmax
  score512_kernel<<<32, 256, 0, stream>>>(Wk, Tq, S);
  norm_dot_kernel<<<64, 256, 0, stream>>>(Wq, Wk, Tq, Tk, inv);
  inv_norm_kernel<<<16, 256, 0, stream>>>(inv);
  softmax_kernel<<<2048, 64, 0, stream>>>(S, inv, resc);

  // fold attention into output projection
  combine_kernel<<<2048, 256, 0, stream>>>(S, WpT, M2T);

  // gated values (x_bf dead after V-gemm/transpose -> reuse as vg)
  gate_kernel<<<32768, 256, 0, stream>>>(v_ws, illu, x_bf);

  // positional branch: fused dwconv->GELU->dwconv (overwrites G region; G dead)
  dwconv_fused_kernel<<<2048, 256, 0, stream>>>(v_ws, c1w, c2w, outp);

  // out = Vg @ M2T^T + bp + out_p  (fp32 output)
  gemm_bt<1><<<dim3(4, 512), 256, 0, stream>>>(x_bf, M2T, out, bp, outp);
}